// Round 7
// baseline (361.706 us; speedup 1.0000x reference)
//
#include <hip/hip_runtime.h>
#include <math.h>

// ---------------------------------------------------------------------------
// GCN: 3 layers (128->32->32->32). CSR build via exact 8-way radix partition
// (hist -> scan -> split), then XCD-local count/fill over bucket regions.
// Algebra: agg[g] = tanh( dis[g] * ( sum_{e:dst=g} hps[src_e] + hps[g] ) + b )
//          where hps = dis ⊙ (h @ W); layer-2/3 GEMMs fused into agg epilogue.
// ---------------------------------------------------------------------------

typedef int   int4v   __attribute__((ext_vector_type(4)));
typedef float float4v __attribute__((ext_vector_type(4)));

#define NBLK 512   // blocks in hist/split (must match binscan's thread count)

// ---- A1: per-block 8-bin histogram of dst ----
__global__ void k_hist(const int* __restrict__ dst, int* __restrict__ blk_hist,
                       int E, float binf) {
    __shared__ int h[8];
    if (threadIdx.x < 8) h[threadIdx.x] = 0;
    __syncthreads();
    const int4v* d4 = (const int4v*)dst;
    int nv = E >> 2;
    int stride = gridDim.x * blockDim.x;
    for (int i = blockIdx.x * blockDim.x + threadIdx.x; i < nv; i += stride) {
        int4v d = __builtin_nontemporal_load(&d4[i]);
#pragma unroll
        for (int j = 0; j < 4; ++j) {
            int b = (int)((float)d[j] * binf); if (b > 7) b = 7;
            atomicAdd(&h[b], 1);
        }
    }
    if (blockIdx.x == 0) {
        for (int e = (nv << 2) + threadIdx.x; e < E; e += blockDim.x) {
            int b = (int)((float)dst[e] * binf); if (b > 7) b = 7;
            atomicAdd(&h[b], 1);
        }
    }
    __syncthreads();
    if (threadIdx.x < 8) blk_hist[threadIdx.x * NBLK + blockIdx.x] = h[threadIdx.x];
}

// ---- A2: per-bin exclusive scan over blocks (one block, NBLK threads) ----
__global__ void k_binscan(int* __restrict__ blk_hist, int* __restrict__ bin_base) {
    __shared__ int s[NBLK];
    __shared__ int stot;
    int tid = threadIdx.x;
    int run = 0;
    for (int q = 0; q < 8; ++q) {
        int v = blk_hist[q * NBLK + tid];
        s[tid] = v;
        __syncthreads();
        for (int off = 1; off < NBLK; off <<= 1) {
            int t = (tid >= off) ? s[tid - off] : 0;
            __syncthreads();
            s[tid] += t;
            __syncthreads();
        }
        blk_hist[q * NBLK + tid] = run + s[tid] - v;  // exclusive + bin base
        if (tid == NBLK - 1) stot = s[tid];
        __syncthreads();
        if (tid == 0) bin_base[q] = run;
        run += stot;
        __syncthreads();
    }
    if (tid == 0) bin_base[8] = run;
}

// ---- A3: scatter edges into bin regions (block-local monotone windows) ----
__global__ void k_split(const int* __restrict__ src, const int* __restrict__ dst,
                        const int* __restrict__ blk_off, uint2* __restrict__ pairs,
                        int E, float binf) {
    __shared__ int goff[8];
    if (threadIdx.x < 8) goff[threadIdx.x] = blk_off[threadIdx.x * NBLK + blockIdx.x];
    __syncthreads();
    const int4v* d4 = (const int4v*)dst;
    const int4v* s4 = (const int4v*)src;
    int nv = E >> 2;
    int stride = gridDim.x * blockDim.x;
    for (int i = blockIdx.x * blockDim.x + threadIdx.x; i < nv; i += stride) {
        int4v d = __builtin_nontemporal_load(&d4[i]);
        int4v s = __builtin_nontemporal_load(&s4[i]);
#pragma unroll
        for (int j = 0; j < 4; ++j) {
            int b = (int)((float)d[j] * binf); if (b > 7) b = 7;
            int pos = atomicAdd(&goff[b], 1);
            pairs[pos] = make_uint2((unsigned)s[j], (unsigned)d[j]);
        }
    }
    if (blockIdx.x == 0) {
        for (int e = (nv << 2) + threadIdx.x; e < E; e += blockDim.x) {
            int b = (int)((float)dst[e] * binf); if (b > 7) b = 7;
            int pos = atomicAdd(&goff[b], 1);
            pairs[pos] = make_uint2((unsigned)src[e], (unsigned)dst[e]);
        }
    }
}

// ---- count in-degree (bucket-region reads, XCD-local cnt atomics) ----
__global__ void k_count(const uint2* __restrict__ pairs, const int* __restrict__ bin_base,
                        int* __restrict__ cnt) {
    int q = blockIdx.x & 7;
    int sub = blockIdx.x >> 3;
    int nsub = gridDim.x >> 3;
    int s0 = bin_base[q], s1 = bin_base[q + 1];
    for (int i = s0 + sub * 256 + threadIdx.x; i < s1; i += nsub * 256)
        atomicAdd(&cnt[pairs[i].y], 1);
}

// ---- scan (rowptr) + dis fused ----
__global__ void k_scan1(const int* __restrict__ cnt, int* __restrict__ rowptr,
                        int* __restrict__ partials, float* __restrict__ dis, int n) {
    __shared__ int s[256];
    int i = blockIdx.x * 256 + threadIdx.x;
    int v = (i < n) ? cnt[i] : 0;
    if (i < n) dis[i] = rsqrtf(1.0f + (float)v);
    s[threadIdx.x] = v;
    __syncthreads();
    for (int off = 1; off < 256; off <<= 1) {
        int t = (threadIdx.x >= off) ? s[threadIdx.x - off] : 0;
        __syncthreads();
        s[threadIdx.x] += t;
        __syncthreads();
    }
    if (i < n) rowptr[i + 1] = s[threadIdx.x];
    if (threadIdx.x == 255) partials[blockIdx.x] = s[255];
}

__global__ void k_scan2(int* __restrict__ partials, int nb) {
    __shared__ int s[512];
    int t = threadIdx.x;
    s[t] = (t < nb) ? partials[t] : 0;
    __syncthreads();
    for (int off = 1; off < 512; off <<= 1) {
        int v = (t >= off) ? s[t - off] : 0;
        __syncthreads();
        s[t] += v;
        __syncthreads();
    }
    if (t < nb) partials[t] = (t == 0) ? 0 : s[t - 1];
}

__global__ void k_scan3(int* __restrict__ rowptr, const int* __restrict__ partials, int n) {
    int i = blockIdx.x * 256 + threadIdx.x;
    if (i < n) rowptr[i + 1] += partials[blockIdx.x];
    if (i == 0) rowptr[0] = 0;
}

// ---- fill CSR (bucket-region reads; cursor/csr slices stay in XCD L2) ----
__global__ void k_fill(const uint2* __restrict__ pairs, const int* __restrict__ bin_base,
                       int* __restrict__ cursor, int* __restrict__ csr_src) {
    int q = blockIdx.x & 7;
    int sub = blockIdx.x >> 3;
    int nsub = gridDim.x >> 3;
    int s0 = bin_base[q], s1 = bin_base[q + 1];
    for (int i = s0 + sub * 256 + threadIdx.x; i < s1; i += nsub * 256) {
        uint2 p = pairs[i];
        int pos = atomicAdd(&cursor[p.y], 1);
        csr_src[pos] = (int)p.x;
    }
}

// ---- layer-1 GEMM: hps[n,32] = dis ⊙ (x[n,128] @ W[128,32]) ----
__global__ void k_gemm1(const float* __restrict__ h, const float* __restrict__ W,
                        const float* __restrict__ dis, float* __restrict__ hps, int n) {
    __shared__ float sW[128 * 32];          // [k][col]
    __shared__ float sh[64 * 132];          // [row][k], pad 132
    int tid = threadIdx.x;
    int row0 = blockIdx.x * 64;
    for (int j = tid; j < 1024; j += 128)
        *(float4*)&sW[j * 4] = *(const float4*)&W[j * 4];
    for (int j = tid; j < 2048; j += 128) {
        int r = j >> 5, c4 = j & 31;
        float4v v = {0.f, 0.f, 0.f, 0.f};
        if (row0 + r < n)
            v = __builtin_nontemporal_load((const float4v*)&h[(size_t)(row0 + r) * 128 + c4 * 4]);
        *(float4v*)&sh[r * 132 + c4 * 4] = v;
    }
    __syncthreads();
    int rg = tid >> 3;      // 0..15 -> 4 rows each
    int cg = tid & 7;       // 0..7  -> 4 cols each
    float acc[4][4] = {};
    const float* shp = &sh[(rg * 4) * 132];
    const float* swp = &sW[cg * 4];
#pragma unroll 8
    for (int k4 = 0; k4 < 32; ++k4) {
        float4 hv[4], wv[4];
#pragma unroll
        for (int r = 0; r < 4; ++r) hv[r] = *(const float4*)&shp[r * 132 + k4 * 4];
#pragma unroll
        for (int t = 0; t < 4; ++t) wv[t] = *(const float4*)&swp[(k4 * 4 + t) * 32];
#pragma unroll
        for (int r = 0; r < 4; ++r) {
            const float hr[4] = {hv[r].x, hv[r].y, hv[r].z, hv[r].w};
#pragma unroll
            for (int t = 0; t < 4; ++t) {
                acc[r][0] += hr[t] * wv[t].x;
                acc[r][1] += hr[t] * wv[t].y;
                acc[r][2] += hr[t] * wv[t].z;
                acc[r][3] += hr[t] * wv[t].w;
            }
        }
    }
#pragma unroll
    for (int r = 0; r < 4; ++r) {
        int row = row0 + rg * 4 + r;
        if (row < n) {
            float dv = dis[row];
            float4 o = make_float4(acc[r][0] * dv, acc[r][1] * dv,
                                   acc[r][2] * dv, acc[r][3] * dv);
            *(float4*)&hps[(size_t)row * 32 + cg * 4] = o;
        }
    }
}

// ---- aggregation (+ optional fused next-layer GEMM epilogue) ----
// 32-lane group per node; 8-way batched gathers for memory-level parallelism.
template <bool FUSE>
__global__ void k_agg(const float* __restrict__ hps, const int* __restrict__ rowptr,
                      const int* __restrict__ csr_src, const float* __restrict__ dis,
                      const float* __restrict__ bias, float* __restrict__ outc,
                      int n, const float* __restrict__ Wn, float* __restrict__ hpsn) {
    __shared__ float sW[32 * 32];
    if (FUSE) {
        for (int i = threadIdx.x; i < 1024; i += 256) sW[i] = Wn[i];
        __syncthreads();
    }
    int g    = (blockIdx.x * blockDim.x + threadIdx.x) >> 5;
    int lane = threadIdx.x & 31;
    if (g >= n) return;
    float acc = hps[(size_t)g * 32 + lane];   // self term
    int e0 = rowptr[g], e1 = rowptr[g + 1];
    int e = e0;
    while (e < e1) {
        int m = e1 - e; if (m > 32) m = 32;
        int sv = (e + lane < e1) ? __builtin_nontemporal_load(&csr_src[e + lane]) : 0;
        int k = 0;
        for (; k + 8 <= m; k += 8) {
            float v[8];
#pragma unroll
            for (int j = 0; j < 8; ++j) {
                int s = __shfl(sv, k + j, 32);
                v[j] = hps[(size_t)s * 32 + lane];
            }
            acc += ((v[0] + v[1]) + (v[2] + v[3])) + ((v[4] + v[5]) + (v[6] + v[7]));
        }
        if (k + 4 <= m) {
            float v[4];
#pragma unroll
            for (int j = 0; j < 4; ++j) {
                int s = __shfl(sv, k + j, 32);
                v[j] = hps[(size_t)s * 32 + lane];
            }
            acc += (v[0] + v[1]) + (v[2] + v[3]);
            k += 4;
        }
        for (; k < m; ++k) {
            int s = __shfl(sv, k, 32);
            acc += hps[(size_t)s * 32 + lane];
        }
        e += m;
    }
    float dg = dis[g];
    float v = tanhf(dg * acc + bias[lane]);
    __builtin_nontemporal_store(v, &outc[(size_t)g * 96 + lane]);
    if (FUSE) {
        float a2 = 0.0f;
#pragma unroll
        for (int k = 0; k < 32; ++k)
            a2 += __shfl(v, k, 32) * sW[k * 32 + lane];
        hpsn[(size_t)g * 32 + lane] = dg * a2;
    }
}

__global__ void k_idx(const int* __restrict__ batch, int* __restrict__ idx, int n, int g) {
    int i = blockIdx.x * blockDim.x + threadIdx.x;
    if (i >= g) return;
    int lo = 0, hi = n;
    while (lo < hi) {
        int mid = (lo + hi) >> 1;
        if (batch[mid] < i) lo = mid + 1; else hi = mid;
    }
    idx[i] = lo;
}

__global__ void k_head(const float* __restrict__ cat, const int* __restrict__ idx,
                       const float* __restrict__ w1, const float* __restrict__ b1,
                       const float* __restrict__ w2, const float* __restrict__ b2,
                       float* __restrict__ out) {
    __shared__ float gv[96];
    __shared__ float s0[128];
    __shared__ float s1[128];
    int g = blockIdx.x, t = threadIdx.x;
    int node = idx[g];
    if (t < 96) gv[t] = cat[(size_t)node * 96 + t];
    __syncthreads();
    float acc = b1[t];
#pragma unroll 8
    for (int i = 0; i < 96; ++i) acc += gv[i] * w1[i * 128 + t];
    float h = fmaxf(acc, 0.0f);
    s0[t] = h * w2[t * 2 + 0];
    s1[t] = h * w2[t * 2 + 1];
    __syncthreads();
    for (int off = 64; off > 0; off >>= 1) {
        if (t < off) { s0[t] += s0[t + off]; s1[t] += s1[t + off]; }
        __syncthreads();
    }
    if (t == 0) {
        float l0 = s0[0] + b2[0];
        float l1 = s1[0] + b2[1];
        float m  = fmaxf(l0, l1);
        float lse = m + logf(expf(l0 - m) + expf(l1 - m));
        out[(size_t)g * 2 + 0] = l0 - lse;
        out[(size_t)g * 2 + 1] = l1 - lse;
    }
}

extern "C" void kernel_launch(void* const* d_in, const int* in_sizes, int n_in,
                              void* d_out, int out_size, void* d_ws, size_t ws_size,
                              hipStream_t stream) {
    const float* x    = (const float*)d_in[0];
    const int*   ei   = (const int*)d_in[1];
    const int*   batch= (const int*)d_in[2];
    const float* W1   = (const float*)d_in[4];
    const float* b1   = (const float*)d_in[5];
    const float* W2   = (const float*)d_in[6];
    const float* b2   = (const float*)d_in[7];
    const float* W3   = (const float*)d_in[8];
    const float* b3   = (const float*)d_in[9];
    const float* l1w  = (const float*)d_in[10];
    const float* l1b  = (const float*)d_in[11];
    const float* l2w  = (const float*)d_in[12];
    const float* l2b  = (const float*)d_in[13];
    float* out = (float*)d_out;

    const int N = in_sizes[0] / 128;
    const int E = in_sizes[1] / 2;
    const int G = out_size / 2;
    const int* src = ei;
    const int* dst = ei + E;
    const float binf = 8.0f / (float)N;

    char* w = (char*)d_ws;
    auto alloc = [&](size_t bytes) {
        char* p = w;
        w += (bytes + 255) & ~(size_t)255;
        return p;
    };
    int*   cnt      = (int*)  alloc((size_t)N * 4);
    float* dis      = (float*)alloc((size_t)N * 4);
    int*   rowptr   = (int*)  alloc((size_t)(N + 1) * 4);
    int*   cursor   = (int*)  alloc((size_t)N * 4);
    int*   partials = (int*)  alloc(((size_t)(N + 255) / 256) * 4);
    int*   csr_src  = (int*)  alloc((size_t)E * 4);
    int*   blk_hist = (int*)  alloc((size_t)8 * NBLK * 4);
    int*   bin_base = (int*)  alloc(9 * 4);
    uint2* pairs    = (uint2*)alloc((size_t)E * 8);
    float* hpsA     = (float*)alloc((size_t)N * 32 * 4);
    float* hpsB     = (float*)alloc((size_t)N * 32 * 4);
    float* catb     = (float*)alloc((size_t)N * 96 * 4);
    int*   idx      = (int*)  alloc((size_t)G * 4);

    const int nb       = (N + 255) / 256;        // scan blocks
    const int nodes_bl = (N * 32 + 255) / 256;   // 8 nodes per 256-thr block
    const int gemm_bl  = (N + 63) / 64;
    const int bkt_bl   = 512;                    // count/fill: 64 blocks/bucket

    hipMemsetAsync(cnt, 0, (size_t)N * 4, stream);

    k_hist<<<NBLK, 256, 0, stream>>>(dst, blk_hist, E, binf);
    k_binscan<<<1, NBLK, 0, stream>>>(blk_hist, bin_base);
    k_split<<<NBLK, 256, 0, stream>>>(src, dst, blk_hist, pairs, E, binf);
    k_count<<<bkt_bl, 256, 0, stream>>>(pairs, bin_base, cnt);
    k_scan1<<<nb, 256, 0, stream>>>(cnt, rowptr, partials, dis, N);
    k_scan2<<<1, 512, 0, stream>>>(partials, nb);
    k_scan3<<<nb, 256, 0, stream>>>(rowptr, partials, N);
    hipMemcpyAsync(cursor, rowptr, (size_t)N * 4, hipMemcpyDeviceToDevice, stream);
    k_fill<<<bkt_bl, 256, 0, stream>>>(pairs, bin_base, cursor, csr_src);

    // layer 1 GEMM, then agg layers (2/3 GEMMs fused into agg epilogues)
    k_gemm1<<<gemm_bl, 128, 0, stream>>>(x, W1, dis, hpsA, N);
    k_agg<true ><<<nodes_bl, 256, 0, stream>>>(hpsA, rowptr, csr_src, dis, b1, catb + 0,  N, W2, hpsB);
    k_agg<true ><<<nodes_bl, 256, 0, stream>>>(hpsB, rowptr, csr_src, dis, b2, catb + 32, N, W3, hpsA);
    k_agg<false><<<nodes_bl, 256, 0, stream>>>(hpsA, rowptr, csr_src, dis, b3, catb + 64, N, nullptr, nullptr);

    k_idx<<<(G + 255) / 256, 256, 0, stream>>>(batch, idx, N, G);
    k_head<<<G, 128, 0, stream>>>(catb, idx, l1w, l1b, l2w, l2b, out);
}

// Round 8
// 335.139 us; speedup vs baseline: 1.0793x; 1.0793x over previous
//
#include <hip/hip_runtime.h>
#include <math.h>

// ---------------------------------------------------------------------------
// GCN: 3 layers (128->32->32->32). CSR build with NO scattered global stores:
//   k_hist  : per-block histogram over 200 fine dst-bins (500 nodes each)
//   k_total/k_sbase/k_coff : bin totals, global bin bases, per-block windows
//   k_split : scatter (src,dst) pairs into 8 coarse buckets (25 bins each) --
//             per-block monotone windows -> large coalesced-ish chunks
//   k_place : one WG per fine bin; streams its bucket's pairs from L2 twice,
//             counts + scans in LDS, scatters csr entries into an LDS stage,
//             then copies to global COALESCED. Also writes rowptr + dis.
// (gfx950 L2 does not merge scattered sub-line stores -- observed ~66MB HBM
//  write traffic for a 6.4MB scatter payload regardless of locality. All
//  global stores here are therefore wave-coalesced.)
// Algebra: agg[g] = tanh( dis[g]*(sum_{e:dst=g} hps[src_e] + hps[g]) + b ),
//          hps = dis ⊙ (h @ W); layer-2/3 GEMMs fused into agg epilogue.
// Assumes N <= 128000 (fine-bin count <= 256); harness uses N=100000.
// ---------------------------------------------------------------------------

typedef int   int4v   __attribute__((ext_vector_type(4)));
typedef float float4v __attribute__((ext_vector_type(4)));

#define NBLK 512            // blocks in hist/split
#define SB   500            // nodes per fine bin (compile-time const division)
#define CAPE 10240          // LDS stage capacity (mean 8000, std ~89 -> safe)

// ---- per-block fine histogram: blk_hist[b*NP + f] ----
__global__ void k_hist(const int* __restrict__ dst, int* __restrict__ blk_hist,
                       int E, int NP) {
    __shared__ int h[256];
    for (int i = threadIdx.x; i < NP; i += 256) h[i] = 0;
    __syncthreads();
    const int4v* d4 = (const int4v*)dst;
    int nv = E >> 2;
    int stride = gridDim.x * blockDim.x;
    for (int i = blockIdx.x * blockDim.x + threadIdx.x; i < nv; i += stride) {
        int4v d = __builtin_nontemporal_load(&d4[i]);
#pragma unroll
        for (int j = 0; j < 4; ++j) atomicAdd(&h[d[j] / SB], 1);
    }
    if (blockIdx.x == 0) {
        for (int e = (nv << 2) + threadIdx.x; e < E; e += blockDim.x)
            atomicAdd(&h[dst[e] / SB], 1);
    }
    __syncthreads();
    for (int i = threadIdx.x; i < NP; i += 256)
        blk_hist[blockIdx.x * NP + i] = h[i];
}

// ---- per-bin totals (block f reduces column f) ----
__global__ void k_total(const int* __restrict__ blk_hist, int* __restrict__ total, int NP) {
    __shared__ int s[256];
    int f = blockIdx.x;
    int acc = 0;
    for (int b = threadIdx.x; b < NBLK; b += 256) acc += blk_hist[b * NP + f];
    s[threadIdx.x] = acc;
    __syncthreads();
    for (int off = 128; off > 0; off >>= 1) {
        if (threadIdx.x < off) s[threadIdx.x] += s[threadIdx.x + off];
        __syncthreads();
    }
    if (threadIdx.x == 0) total[f] = s[0];
}

// ---- exclusive scan of totals -> sbase[0..NP], sbase[NP]=E ----
__global__ void k_sbase(const int* __restrict__ total, int* __restrict__ sbase, int NP) {
    __shared__ int s[256];
    int t = threadIdx.x;
    int v = (t < NP) ? total[t] : 0;
    s[t] = v;
    __syncthreads();
    for (int off = 1; off < 256; off <<= 1) {
        int u = (t >= off) ? s[t - off] : 0;
        __syncthreads();
        s[t] += u;
        __syncthreads();
    }
    if (t < NP) sbase[t] = s[t] - v;
    if (t == NP - 1) sbase[NP] = s[t];
}

// ---- per-block coarse-bucket window offsets for k_split ----
__global__ void k_coff(const int* __restrict__ blk_hist, const int* __restrict__ sbase,
                       int* __restrict__ cblk_off, int NP, int bpb) {
    __shared__ int s[NBLK];
    int b = threadIdx.x;
    int csum[8];
#pragma unroll
    for (int q = 0; q < 8; ++q) {
        int a = 0;
        for (int f = q * bpb; f < (q + 1) * bpb; ++f) a += blk_hist[b * NP + f];
        csum[q] = a;
    }
    for (int q = 0; q < 8; ++q) {
        int v = csum[q];
        s[b] = v;
        __syncthreads();
        for (int off = 1; off < NBLK; off <<= 1) {
            int u = (b >= off) ? s[b - off] : 0;
            __syncthreads();
            s[b] += u;
            __syncthreads();
        }
        cblk_off[b * 8 + q] = sbase[q * bpb] + (s[b] - v);
        __syncthreads();
    }
}

// ---- scatter edges into 8 coarse bucket regions ----
__global__ void k_split(const int* __restrict__ src, const int* __restrict__ dst,
                        const int* __restrict__ cblk_off, uint2* __restrict__ pairs,
                        int E, int bpb) {
    __shared__ int goff[8];
    if (threadIdx.x < 8) goff[threadIdx.x] = cblk_off[blockIdx.x * 8 + threadIdx.x];
    __syncthreads();
    const int4v* d4 = (const int4v*)dst;
    const int4v* s4 = (const int4v*)src;
    int nv = E >> 2;
    int stride = gridDim.x * blockDim.x;
    for (int i = blockIdx.x * blockDim.x + threadIdx.x; i < nv; i += stride) {
        int4v d = __builtin_nontemporal_load(&d4[i]);
        int4v s = __builtin_nontemporal_load(&s4[i]);
#pragma unroll
        for (int j = 0; j < 4; ++j) {
            int q = (d[j] / SB) / bpb;
            int pos = atomicAdd(&goff[q], 1);
            pairs[pos] = make_uint2((unsigned)s[j], (unsigned)d[j]);
        }
    }
    if (blockIdx.x == 0) {
        for (int e = (nv << 2) + threadIdx.x; e < E; e += blockDim.x) {
            int q = (dst[e] / SB) / bpb;
            int pos = atomicAdd(&goff[q], 1);
            pairs[pos] = make_uint2((unsigned)src[e], (unsigned)dst[e]);
        }
    }
}

// ---- place: per fine bin, LDS count/scan/scatter, coalesced global writes ----
__global__ void __launch_bounds__(512)
k_place(const uint2* __restrict__ pairs, const int* __restrict__ sbase,
        int* __restrict__ rowptr, float* __restrict__ dis,
        int* __restrict__ csr_src, int N, int NP, int bpb) {
    __shared__ int lcnt[SB];
    __shared__ int lrp[SB + 1];
    __shared__ int sc[512];
    __shared__ int stage[CAPE];
    int b = blockIdx.x;
    int f = (b & 7) * bpb + (b >> 3);       // XCD-aligned bin remap (NP==8*bpb)
    int lo = f * SB;
    if (lo >= N) return;
    int hi = lo + SB; if (hi > N) hi = N;
    int sbc = hi - lo;
    int q = f / bpb;
    int p0 = sbase[q * bpb], p1 = sbase[(q + 1) * bpb];
    int base = sbase[f];
    int tid = threadIdx.x;
    for (int i = tid; i < sbc; i += 512) lcnt[i] = 0;
    __syncthreads();
    // pass A: count (4-way unrolled for MLP)
    {
        int i = p0 + tid;
        for (; i + 3 * 512 < p1; i += 4 * 512) {
            uint2 a = pairs[i], c = pairs[i + 512], d = pairs[i + 1024], e = pairs[i + 1536];
            unsigned la = a.y - lo, lc = c.y - lo, ld = d.y - lo, le = e.y - lo;
            if (la < (unsigned)sbc) atomicAdd(&lcnt[la], 1);
            if (lc < (unsigned)sbc) atomicAdd(&lcnt[lc], 1);
            if (ld < (unsigned)sbc) atomicAdd(&lcnt[ld], 1);
            if (le < (unsigned)sbc) atomicAdd(&lcnt[le], 1);
        }
        for (; i < p1; i += 512) {
            unsigned ly = pairs[i].y - lo;
            if (ly < (unsigned)sbc) atomicAdd(&lcnt[ly], 1);
        }
    }
    __syncthreads();
    // dis (coalesced)
    for (int i = tid; i < sbc; i += 512) dis[lo + i] = rsqrtf(1.0f + (float)lcnt[i]);
    // exclusive scan lcnt -> lrp
    int v = (tid < sbc) ? lcnt[tid] : 0;
    sc[tid] = v;
    __syncthreads();
    for (int off = 1; off < 512; off <<= 1) {
        int u = (tid >= off) ? sc[tid - off] : 0;
        __syncthreads();
        sc[tid] += u;
        __syncthreads();
    }
    if (tid < sbc) lrp[tid] = sc[tid] - v;
    if (tid == 511) lrp[sbc] = sc[511];
    __syncthreads();
    int T = lrp[sbc];
    // rowptr (coalesced)
    for (int i = tid; i < sbc; i += 512) rowptr[lo + i] = base + lrp[i];
    if (hi == N && tid == 0) rowptr[N] = base + T;
    // pass B: scatter into LDS stage (or global fallback if T > CAPE)
    for (int i = tid; i < sbc; i += 512) lcnt[i] = 0;
    __syncthreads();
    {
        int i = p0 + tid;
        for (; i + 3 * 512 < p1; i += 4 * 512) {
            uint2 a = pairs[i], c = pairs[i + 512], d = pairs[i + 1024], e = pairs[i + 1536];
#pragma unroll
            for (int j = 0; j < 4; ++j) {
                uint2 p = (j == 0) ? a : (j == 1) ? c : (j == 2) ? d : e;
                unsigned ly = p.y - lo;
                if (ly < (unsigned)sbc) {
                    int slot = lrp[ly] + atomicAdd(&lcnt[ly], 1);
                    if (T <= CAPE) stage[slot] = (int)p.x;
                    else           csr_src[base + slot] = (int)p.x;
                }
            }
        }
        for (; i < p1; i += 512) {
            uint2 p = pairs[i];
            unsigned ly = p.y - lo;
            if (ly < (unsigned)sbc) {
                int slot = lrp[ly] + atomicAdd(&lcnt[ly], 1);
                if (T <= CAPE) stage[slot] = (int)p.x;
                else           csr_src[base + slot] = (int)p.x;
            }
        }
    }
    __syncthreads();
    if (T <= CAPE)
        for (int j = tid; j < T; j += 512) csr_src[base + j] = stage[j];
}

// ---- layer-1 GEMM: hps[n,32] = dis ⊙ (x[n,128] @ W[128,32]) ----
__global__ void k_gemm1(const float* __restrict__ h, const float* __restrict__ W,
                        const float* __restrict__ dis, float* __restrict__ hps, int n) {
    __shared__ float sW[128 * 32];          // [k][col]
    __shared__ float sh[64 * 132];          // [row][k], pad 132
    int tid = threadIdx.x;
    int row0 = blockIdx.x * 64;
    for (int j = tid; j < 1024; j += 128)
        *(float4*)&sW[j * 4] = *(const float4*)&W[j * 4];
    for (int j = tid; j < 2048; j += 128) {
        int r = j >> 5, c4 = j & 31;
        float4v v = {0.f, 0.f, 0.f, 0.f};
        if (row0 + r < n)
            v = __builtin_nontemporal_load((const float4v*)&h[(size_t)(row0 + r) * 128 + c4 * 4]);
        *(float4v*)&sh[r * 132 + c4 * 4] = v;
    }
    __syncthreads();
    int rg = tid >> 3;      // 0..15 -> 4 rows each
    int cg = tid & 7;       // 0..7  -> 4 cols each
    float acc[4][4] = {};
    const float* shp = &sh[(rg * 4) * 132];
    const float* swp = &sW[cg * 4];
#pragma unroll 8
    for (int k4 = 0; k4 < 32; ++k4) {
        float4 hv[4], wv[4];
#pragma unroll
        for (int r = 0; r < 4; ++r) hv[r] = *(const float4*)&shp[r * 132 + k4 * 4];
#pragma unroll
        for (int t = 0; t < 4; ++t) wv[t] = *(const float4*)&swp[(k4 * 4 + t) * 32];
#pragma unroll
        for (int r = 0; r < 4; ++r) {
            const float hr[4] = {hv[r].x, hv[r].y, hv[r].z, hv[r].w};
#pragma unroll
            for (int t = 0; t < 4; ++t) {
                acc[r][0] += hr[t] * wv[t].x;
                acc[r][1] += hr[t] * wv[t].y;
                acc[r][2] += hr[t] * wv[t].z;
                acc[r][3] += hr[t] * wv[t].w;
            }
        }
    }
#pragma unroll
    for (int r = 0; r < 4; ++r) {
        int row = row0 + rg * 4 + r;
        if (row < n) {
            float dv = dis[row];
            float4 o = make_float4(acc[r][0] * dv, acc[r][1] * dv,
                                   acc[r][2] * dv, acc[r][3] * dv);
            *(float4*)&hps[(size_t)row * 32 + cg * 4] = o;
        }
    }
}

// ---- aggregation (+ optional fused next-layer GEMM epilogue) ----
template <bool FUSE>
__global__ void k_agg(const float* __restrict__ hps, const int* __restrict__ rowptr,
                      const int* __restrict__ csr_src, const float* __restrict__ dis,
                      const float* __restrict__ bias, float* __restrict__ outc,
                      int n, const float* __restrict__ Wn, float* __restrict__ hpsn) {
    __shared__ float sW[32 * 32];
    if (FUSE) {
        for (int i = threadIdx.x; i < 1024; i += 256) sW[i] = Wn[i];
        __syncthreads();
    }
    int g    = (blockIdx.x * blockDim.x + threadIdx.x) >> 5;
    int lane = threadIdx.x & 31;
    if (g >= n) return;
    float acc = hps[(size_t)g * 32 + lane];   // self term
    int e0 = rowptr[g], e1 = rowptr[g + 1];
    int e = e0;
    while (e < e1) {
        int m = e1 - e; if (m > 32) m = 32;
        int sv = (e + lane < e1) ? __builtin_nontemporal_load(&csr_src[e + lane]) : 0;
        int k = 0;
        for (; k + 8 <= m; k += 8) {
            float v[8];
#pragma unroll
            for (int j = 0; j < 8; ++j) {
                int s = __shfl(sv, k + j, 32);
                v[j] = hps[(size_t)s * 32 + lane];
            }
            acc += ((v[0] + v[1]) + (v[2] + v[3])) + ((v[4] + v[5]) + (v[6] + v[7]));
        }
        if (k + 4 <= m) {
            float v[4];
#pragma unroll
            for (int j = 0; j < 4; ++j) {
                int s = __shfl(sv, k + j, 32);
                v[j] = hps[(size_t)s * 32 + lane];
            }
            acc += (v[0] + v[1]) + (v[2] + v[3]);
            k += 4;
        }
        for (; k < m; ++k) {
            int s = __shfl(sv, k, 32);
            acc += hps[(size_t)s * 32 + lane];
        }
        e += m;
    }
    float dg = dis[g];
    float v = tanhf(dg * acc + bias[lane]);
    __builtin_nontemporal_store(v, &outc[(size_t)g * 96 + lane]);
    if (FUSE) {
        float a2 = 0.0f;
#pragma unroll
        for (int k = 0; k < 32; ++k)
            a2 += __shfl(v, k, 32) * sW[k * 32 + lane];
        hpsn[(size_t)g * 32 + lane] = dg * a2;
    }
}

__global__ void k_idx(const int* __restrict__ batch, int* __restrict__ idx, int n, int g) {
    int i = blockIdx.x * blockDim.x + threadIdx.x;
    if (i >= g) return;
    int lo = 0, hi = n;
    while (lo < hi) {
        int mid = (lo + hi) >> 1;
        if (batch[mid] < i) lo = mid + 1; else hi = mid;
    }
    idx[i] = lo;
}

__global__ void k_head(const float* __restrict__ cat, const int* __restrict__ idx,
                       const float* __restrict__ w1, const float* __restrict__ b1,
                       const float* __restrict__ w2, const float* __restrict__ b2,
                       float* __restrict__ out) {
    __shared__ float gv[96];
    __shared__ float s0[128];
    __shared__ float s1[128];
    int g = blockIdx.x, t = threadIdx.x;
    int node = idx[g];
    if (t < 96) gv[t] = cat[(size_t)node * 96 + t];
    __syncthreads();
    float acc = b1[t];
#pragma unroll 8
    for (int i = 0; i < 96; ++i) acc += gv[i] * w1[i * 128 + t];
    float h = fmaxf(acc, 0.0f);
    s0[t] = h * w2[t * 2 + 0];
    s1[t] = h * w2[t * 2 + 1];
    __syncthreads();
    for (int off = 64; off > 0; off >>= 1) {
        if (t < off) { s0[t] += s0[t + off]; s1[t] += s1[t + off]; }
        __syncthreads();
    }
    if (t == 0) {
        float l0 = s0[0] + b2[0];
        float l1 = s1[0] + b2[1];
        float m  = fmaxf(l0, l1);
        float lse = m + logf(expf(l0 - m) + expf(l1 - m));
        out[(size_t)g * 2 + 0] = l0 - lse;
        out[(size_t)g * 2 + 1] = l1 - lse;
    }
}

extern "C" void kernel_launch(void* const* d_in, const int* in_sizes, int n_in,
                              void* d_out, int out_size, void* d_ws, size_t ws_size,
                              hipStream_t stream) {
    const float* x    = (const float*)d_in[0];
    const int*   ei   = (const int*)d_in[1];
    const int*   batch= (const int*)d_in[2];
    const float* W1   = (const float*)d_in[4];
    const float* b1   = (const float*)d_in[5];
    const float* W2   = (const float*)d_in[6];
    const float* b2   = (const float*)d_in[7];
    const float* W3   = (const float*)d_in[8];
    const float* b3   = (const float*)d_in[9];
    const float* l1w  = (const float*)d_in[10];
    const float* l1b  = (const float*)d_in[11];
    const float* l2w  = (const float*)d_in[12];
    const float* l2b  = (const float*)d_in[13];
    float* out = (float*)d_out;

    const int N = in_sizes[0] / 128;
    const int E = in_sizes[1] / 2;
    const int G = out_size / 2;
    const int* src = ei;
    const int* dst = ei + E;

    const int NP  = (((N + SB - 1) / SB) + 7) & ~7;   // padded fine-bin count (=200)
    const int bpb = NP / 8;                            // fine bins per coarse bucket

    char* w = (char*)d_ws;
    auto alloc = [&](size_t bytes) {
        char* p = w;
        w += (bytes + 255) & ~(size_t)255;
        return p;
    };
    float* dis      = (float*)alloc((size_t)N * 4);
    int*   rowptr   = (int*)  alloc((size_t)(N + 1) * 4);
    int*   csr_src  = (int*)  alloc((size_t)E * 4);
    int*   blk_hist = (int*)  alloc((size_t)NBLK * NP * 4);
    int*   total    = (int*)  alloc((size_t)NP * 4);
    int*   sbase    = (int*)  alloc((size_t)(NP + 1) * 4);
    int*   cblk_off = (int*)  alloc((size_t)NBLK * 8 * 4);
    uint2* pairs    = (uint2*)alloc((size_t)E * 8);
    float* hpsA     = (float*)alloc((size_t)N * 32 * 4);
    float* hpsB     = (float*)alloc((size_t)N * 32 * 4);
    float* catb     = (float*)alloc((size_t)N * 96 * 4);
    int*   idx      = (int*)  alloc((size_t)G * 4);

    const int nodes_bl = (N * 32 + 255) / 256;   // 8 nodes per 256-thr block
    const int gemm_bl  = (N + 63) / 64;

    k_hist <<<NBLK, 256, 0, stream>>>(dst, blk_hist, E, NP);
    k_total<<<NP,   256, 0, stream>>>(blk_hist, total, NP);
    k_sbase<<<1,    256, 0, stream>>>(total, sbase, NP);
    k_coff <<<1,   NBLK, 0, stream>>>(blk_hist, sbase, cblk_off, NP, bpb);
    k_split<<<NBLK, 256, 0, stream>>>(src, dst, cblk_off, pairs, E, bpb);
    k_place<<<NP,   512, 0, stream>>>(pairs, sbase, rowptr, dis, csr_src, N, NP, bpb);

    // layer 1 GEMM, then agg layers (2/3 GEMMs fused into agg epilogues)
    k_gemm1<<<gemm_bl, 128, 0, stream>>>(x, W1, dis, hpsA, N);
    k_agg<true ><<<nodes_bl, 256, 0, stream>>>(hpsA, rowptr, csr_src, dis, b1, catb + 0,  N, W2, hpsB);
    k_agg<true ><<<nodes_bl, 256, 0, stream>>>(hpsB, rowptr, csr_src, dis, b2, catb + 32, N, W3, hpsA);
    k_agg<false><<<nodes_bl, 256, 0, stream>>>(hpsA, rowptr, csr_src, dis, b3, catb + 64, N, nullptr, nullptr);

    k_idx<<<(G + 255) / 256, 256, 0, stream>>>(batch, idx, N, G);
    k_head<<<G, 128, 0, stream>>>(catb, idx, l1w, l1b, l2w, l2b, out);
}

// Round 9
// 234.788 us; speedup vs baseline: 1.5406x; 1.4274x over previous
//
#include <hip/hip_runtime.h>
#include <math.h>

// ---------------------------------------------------------------------------
// GCN: 3 layers (128->32->32->32). CSR build with NO scattered global stores
// and NO redundant re-reads:
//   k_hist   : per-block histogram over 200 fine dst-bins (500 nodes each)
//   k_total  : per-bin totals     k_sbase : global bin bases (scan)
//   k_binoff : per-(block,bin) write windows (scan over blocks per bin)
//   k_split  : scatter (src,dst) pairs DIRECTLY into fine-bin regions;
//              per-(block,bin) windows are monotone -> mostly full lines
//   k_place  : one WG per fine bin; reads ONLY its bin region (2 passes from
//              L2), counts + scans in LDS, scatters csr into an LDS stage,
//              copies out COALESCED; also writes rowptr + dis.
// (gfx950 L2 does not merge scattered sub-line stores: ~66MB HBM writes for a
//  6.4MB scatter payload regardless of locality. All global stores here are
//  wave-coalesced or near-full-line windows.)
// Algebra: agg[g] = tanh( dis[g]*(sum_{e:dst=g} hps[src_e] + hps[g]) + b ),
//          hps = dis ⊙ (h @ W); layer-2/3 GEMMs fused into agg epilogue.
// Assumes N <= 128000 (fine-bin count <= 256); harness uses N=100000.
// ---------------------------------------------------------------------------

typedef int   int4v   __attribute__((ext_vector_type(4)));
typedef float float4v __attribute__((ext_vector_type(4)));

#define NBLK 256            // blocks in hist/split (hist partition == split partition)
#define SB   500            // nodes per fine bin
#define CAPE 10240          // LDS stage capacity (bin mean 8000, std ~90)

// ---- per-block fine histogram: blk_hist[b*NP + f] ----
__global__ void k_hist(const int* __restrict__ dst, int* __restrict__ blk_hist,
                       int E, int NP) {
    __shared__ int h[256];
    for (int i = threadIdx.x; i < NP; i += 256) h[i] = 0;
    __syncthreads();
    const int4v* d4 = (const int4v*)dst;
    int nv = E >> 2;
    int stride = gridDim.x * blockDim.x;
    for (int i = blockIdx.x * blockDim.x + threadIdx.x; i < nv; i += stride) {
        int4v d = __builtin_nontemporal_load(&d4[i]);
#pragma unroll
        for (int j = 0; j < 4; ++j) atomicAdd(&h[d[j] / SB], 1);
    }
    if (blockIdx.x == 0) {
        for (int e = (nv << 2) + threadIdx.x; e < E; e += blockDim.x)
            atomicAdd(&h[dst[e] / SB], 1);
    }
    __syncthreads();
    for (int i = threadIdx.x; i < NP; i += 256)
        blk_hist[blockIdx.x * NP + i] = h[i];
}

// ---- per-bin totals (block f reduces column f over NBLK blocks) ----
__global__ void k_total(const int* __restrict__ blk_hist, int* __restrict__ total, int NP) {
    __shared__ int s[256];
    int f = blockIdx.x;
    int acc = 0;
    for (int b = threadIdx.x; b < NBLK; b += 256) acc += blk_hist[b * NP + f];
    s[threadIdx.x] = acc;
    __syncthreads();
    for (int off = 128; off > 0; off >>= 1) {
        if (threadIdx.x < off) s[threadIdx.x] += s[threadIdx.x + off];
        __syncthreads();
    }
    if (threadIdx.x == 0) total[f] = s[0];
}

// ---- exclusive scan of totals -> sbase[0..NP], sbase[NP]=E ----
__global__ void k_sbase(const int* __restrict__ total, int* __restrict__ sbase, int NP) {
    __shared__ int s[256];
    int t = threadIdx.x;
    int v = (t < NP) ? total[t] : 0;
    s[t] = v;
    __syncthreads();
    for (int off = 1; off < 256; off <<= 1) {
        int u = (t >= off) ? s[t - off] : 0;
        __syncthreads();
        s[t] += u;
        __syncthreads();
    }
    if (t < NP) sbase[t] = s[t] - v;
    if (t == NP - 1) sbase[NP] = s[t];
}

// ---- per-(block,bin) window offsets: blk_off[b*NP+f] (block f scans bin f) ----
__global__ void k_binoff(const int* __restrict__ blk_hist, const int* __restrict__ sbase,
                         int* __restrict__ blk_off, int NP) {
    __shared__ int s[NBLK];
    int f = blockIdx.x;
    int b = threadIdx.x;      // NBLK threads
    int v = blk_hist[b * NP + f];
    s[b] = v;
    __syncthreads();
    for (int off = 1; off < NBLK; off <<= 1) {
        int u = (b >= off) ? s[b - off] : 0;
        __syncthreads();
        s[b] += u;
        __syncthreads();
    }
    blk_off[b * NP + f] = sbase[f] + s[b] - v;
}

// ---- scatter edges directly into fine-bin regions ----
__global__ void k_split(const int* __restrict__ src, const int* __restrict__ dst,
                        const int* __restrict__ blk_off, uint2* __restrict__ pairs,
                        int E, int NP) {
    __shared__ int goff[256];
    for (int f = threadIdx.x; f < NP; f += 256)
        goff[f] = blk_off[blockIdx.x * NP + f];
    __syncthreads();
    const int4v* d4 = (const int4v*)dst;
    const int4v* s4 = (const int4v*)src;
    int nv = E >> 2;
    int stride = gridDim.x * blockDim.x;
    for (int i = blockIdx.x * blockDim.x + threadIdx.x; i < nv; i += stride) {
        int4v d = __builtin_nontemporal_load(&d4[i]);
        int4v s = __builtin_nontemporal_load(&s4[i]);
#pragma unroll
        for (int j = 0; j < 4; ++j) {
            int f = d[j] / SB;
            int pos = atomicAdd(&goff[f], 1);
            pairs[pos] = make_uint2((unsigned)s[j], (unsigned)d[j]);
        }
    }
    if (blockIdx.x == 0) {
        for (int e = (nv << 2) + threadIdx.x; e < E; e += blockDim.x) {
            int f = dst[e] / SB;
            int pos = atomicAdd(&goff[f], 1);
            pairs[pos] = make_uint2((unsigned)src[e], (unsigned)dst[e]);
        }
    }
}

// ---- place: per fine bin, LDS count/scan/scatter, coalesced global writes ----
__global__ void __launch_bounds__(512)
k_place(const uint2* __restrict__ pairs, const int* __restrict__ sbase,
        int* __restrict__ rowptr, float* __restrict__ dis,
        int* __restrict__ csr_src, int N, int NP) {
    __shared__ int lcnt[SB];
    __shared__ int lrp[SB + 1];
    __shared__ int sc[512];
    __shared__ int stage[CAPE];
    int f = blockIdx.x;
    int lo = f * SB;
    if (lo >= N) return;
    int hi = lo + SB; if (hi > N) hi = N;
    int sbc = hi - lo;
    int p0 = sbase[f], p1 = sbase[f + 1];
    int base = p0;
    int tid = threadIdx.x;
    for (int i = tid; i < sbc; i += 512) lcnt[i] = 0;
    __syncthreads();
    // pass A: count (4-way unrolled for MLP)
    {
        int i = p0 + tid;
        for (; i + 3 * 512 < p1; i += 4 * 512) {
            uint2 a = pairs[i], c = pairs[i + 512], d = pairs[i + 1024], e = pairs[i + 1536];
            unsigned la = a.y - lo, lc = c.y - lo, ld = d.y - lo, le = e.y - lo;
            if (la < (unsigned)sbc) atomicAdd(&lcnt[la], 1);
            if (lc < (unsigned)sbc) atomicAdd(&lcnt[lc], 1);
            if (ld < (unsigned)sbc) atomicAdd(&lcnt[ld], 1);
            if (le < (unsigned)sbc) atomicAdd(&lcnt[le], 1);
        }
        for (; i < p1; i += 512) {
            unsigned ly = pairs[i].y - lo;
            if (ly < (unsigned)sbc) atomicAdd(&lcnt[ly], 1);
        }
    }
    __syncthreads();
    // dis (coalesced)
    for (int i = tid; i < sbc; i += 512) dis[lo + i] = rsqrtf(1.0f + (float)lcnt[i]);
    // exclusive scan lcnt -> lrp
    int v = (tid < sbc) ? lcnt[tid] : 0;
    sc[tid] = v;
    __syncthreads();
    for (int off = 1; off < 512; off <<= 1) {
        int u = (tid >= off) ? sc[tid - off] : 0;
        __syncthreads();
        sc[tid] += u;
        __syncthreads();
    }
    if (tid < sbc) lrp[tid] = sc[tid] - v;
    if (tid == 511) lrp[sbc] = sc[511];
    __syncthreads();
    int T = lrp[sbc];
    // rowptr (coalesced)
    for (int i = tid; i < sbc; i += 512) rowptr[lo + i] = base + lrp[i];
    if (hi == N && tid == 0) rowptr[N] = base + T;
    // pass B: scatter into LDS stage (or global fallback if T > CAPE)
    for (int i = tid; i < sbc; i += 512) lcnt[i] = 0;
    __syncthreads();
    {
        int i = p0 + tid;
        for (; i + 3 * 512 < p1; i += 4 * 512) {
            uint2 a = pairs[i], c = pairs[i + 512], d = pairs[i + 1024], e = pairs[i + 1536];
#pragma unroll
            for (int j = 0; j < 4; ++j) {
                uint2 p = (j == 0) ? a : (j == 1) ? c : (j == 2) ? d : e;
                unsigned ly = p.y - lo;
                if (ly < (unsigned)sbc) {
                    int slot = lrp[ly] + atomicAdd(&lcnt[ly], 1);
                    if (T <= CAPE) stage[slot] = (int)p.x;
                    else           csr_src[base + slot] = (int)p.x;
                }
            }
        }
        for (; i < p1; i += 512) {
            uint2 p = pairs[i];
            unsigned ly = p.y - lo;
            if (ly < (unsigned)sbc) {
                int slot = lrp[ly] + atomicAdd(&lcnt[ly], 1);
                if (T <= CAPE) stage[slot] = (int)p.x;
                else           csr_src[base + slot] = (int)p.x;
            }
        }
    }
    __syncthreads();
    if (T <= CAPE)
        for (int j = tid; j < T; j += 512) csr_src[base + j] = stage[j];
}

// ---- layer-1 GEMM: hps[n,32] = dis ⊙ (x[n,128] @ W[128,32]) ----
__global__ void k_gemm1(const float* __restrict__ h, const float* __restrict__ W,
                        const float* __restrict__ dis, float* __restrict__ hps, int n) {
    __shared__ float sW[128 * 32];          // [k][col]
    __shared__ float sh[64 * 132];          // [row][k], pad 132
    int tid = threadIdx.x;
    int row0 = blockIdx.x * 64;
    for (int j = tid; j < 1024; j += 128)
        *(float4*)&sW[j * 4] = *(const float4*)&W[j * 4];
    for (int j = tid; j < 2048; j += 128) {
        int r = j >> 5, c4 = j & 31;
        float4v v = {0.f, 0.f, 0.f, 0.f};
        if (row0 + r < n)
            v = __builtin_nontemporal_load((const float4v*)&h[(size_t)(row0 + r) * 128 + c4 * 4]);
        *(float4v*)&sh[r * 132 + c4 * 4] = v;
    }
    __syncthreads();
    int rg = tid >> 3;      // 0..15 -> 4 rows each
    int cg = tid & 7;       // 0..7  -> 4 cols each
    float acc[4][4] = {};
    const float* shp = &sh[(rg * 4) * 132];
    const float* swp = &sW[cg * 4];
#pragma unroll 8
    for (int k4 = 0; k4 < 32; ++k4) {
        float4 hv[4], wv[4];
#pragma unroll
        for (int r = 0; r < 4; ++r) hv[r] = *(const float4*)&shp[r * 132 + k4 * 4];
#pragma unroll
        for (int t = 0; t < 4; ++t) wv[t] = *(const float4*)&swp[(k4 * 4 + t) * 32];
#pragma unroll
        for (int r = 0; r < 4; ++r) {
            const float hr[4] = {hv[r].x, hv[r].y, hv[r].z, hv[r].w};
#pragma unroll
            for (int t = 0; t < 4; ++t) {
                acc[r][0] += hr[t] * wv[t].x;
                acc[r][1] += hr[t] * wv[t].y;
                acc[r][2] += hr[t] * wv[t].z;
                acc[r][3] += hr[t] * wv[t].w;
            }
        }
    }
#pragma unroll
    for (int r = 0; r < 4; ++r) {
        int row = row0 + rg * 4 + r;
        if (row < n) {
            float dv = dis[row];
            float4 o = make_float4(acc[r][0] * dv, acc[r][1] * dv,
                                   acc[r][2] * dv, acc[r][3] * dv);
            *(float4*)&hps[(size_t)row * 32 + cg * 4] = o;
        }
    }
}

// ---- aggregation (+ optional fused next-layer GEMM epilogue) ----
template <bool FUSE>
__global__ void k_agg(const float* __restrict__ hps, const int* __restrict__ rowptr,
                      const int* __restrict__ csr_src, const float* __restrict__ dis,
                      const float* __restrict__ bias, float* __restrict__ outc,
                      int n, const float* __restrict__ Wn, float* __restrict__ hpsn) {
    __shared__ float sW[32 * 32];
    if (FUSE) {
        for (int i = threadIdx.x; i < 1024; i += 256) sW[i] = Wn[i];
        __syncthreads();
    }
    int g    = (blockIdx.x * blockDim.x + threadIdx.x) >> 5;
    int lane = threadIdx.x & 31;
    if (g >= n) return;
    float acc = hps[(size_t)g * 32 + lane];   // self term
    int e0 = rowptr[g], e1 = rowptr[g + 1];
    int e = e0;
    while (e < e1) {
        int m = e1 - e; if (m > 32) m = 32;
        int sv = (e + lane < e1) ? __builtin_nontemporal_load(&csr_src[e + lane]) : 0;
        int k = 0;
        for (; k + 8 <= m; k += 8) {
            float v[8];
#pragma unroll
            for (int j = 0; j < 8; ++j) {
                int s = __shfl(sv, k + j, 32);
                v[j] = hps[(size_t)s * 32 + lane];
            }
            acc += ((v[0] + v[1]) + (v[2] + v[3])) + ((v[4] + v[5]) + (v[6] + v[7]));
        }
        if (k + 4 <= m) {
            float v[4];
#pragma unroll
            for (int j = 0; j < 4; ++j) {
                int s = __shfl(sv, k + j, 32);
                v[j] = hps[(size_t)s * 32 + lane];
            }
            acc += (v[0] + v[1]) + (v[2] + v[3]);
            k += 4;
        }
        for (; k < m; ++k) {
            int s = __shfl(sv, k, 32);
            acc += hps[(size_t)s * 32 + lane];
        }
        e += m;
    }
    float dg = dis[g];
    float v = tanhf(dg * acc + bias[lane]);
    __builtin_nontemporal_store(v, &outc[(size_t)g * 96 + lane]);
    if (FUSE) {
        float a2 = 0.0f;
#pragma unroll
        for (int k = 0; k < 32; ++k)
            a2 += __shfl(v, k, 32) * sW[k * 32 + lane];
        hpsn[(size_t)g * 32 + lane] = dg * a2;
    }
}

__global__ void k_idx(const int* __restrict__ batch, int* __restrict__ idx, int n, int g) {
    int i = blockIdx.x * blockDim.x + threadIdx.x;
    if (i >= g) return;
    int lo = 0, hi = n;
    while (lo < hi) {
        int mid = (lo + hi) >> 1;
        if (batch[mid] < i) lo = mid + 1; else hi = mid;
    }
    idx[i] = lo;
}

__global__ void k_head(const float* __restrict__ cat, const int* __restrict__ idx,
                       const float* __restrict__ w1, const float* __restrict__ b1,
                       const float* __restrict__ w2, const float* __restrict__ b2,
                       float* __restrict__ out) {
    __shared__ float gv[96];
    __shared__ float s0[128];
    __shared__ float s1[128];
    int g = blockIdx.x, t = threadIdx.x;
    int node = idx[g];
    if (t < 96) gv[t] = cat[(size_t)node * 96 + t];
    __syncthreads();
    float acc = b1[t];
#pragma unroll 8
    for (int i = 0; i < 96; ++i) acc += gv[i] * w1[i * 128 + t];
    float h = fmaxf(acc, 0.0f);
    s0[t] = h * w2[t * 2 + 0];
    s1[t] = h * w2[t * 2 + 1];
    __syncthreads();
    for (int off = 64; off > 0; off >>= 1) {
        if (t < off) { s0[t] += s0[t + off]; s1[t] += s1[t + off]; }
        __syncthreads();
    }
    if (t == 0) {
        float l0 = s0[0] + b2[0];
        float l1 = s1[0] + b2[1];
        float m  = fmaxf(l0, l1);
        float lse = m + logf(expf(l0 - m) + expf(l1 - m));
        out[(size_t)g * 2 + 0] = l0 - lse;
        out[(size_t)g * 2 + 1] = l1 - lse;
    }
}

extern "C" void kernel_launch(void* const* d_in, const int* in_sizes, int n_in,
                              void* d_out, int out_size, void* d_ws, size_t ws_size,
                              hipStream_t stream) {
    const float* x    = (const float*)d_in[0];
    const int*   ei   = (const int*)d_in[1];
    const int*   batch= (const int*)d_in[2];
    const float* W1   = (const float*)d_in[4];
    const float* b1   = (const float*)d_in[5];
    const float* W2   = (const float*)d_in[6];
    const float* b2   = (const float*)d_in[7];
    const float* W3   = (const float*)d_in[8];
    const float* b3   = (const float*)d_in[9];
    const float* l1w  = (const float*)d_in[10];
    const float* l1b  = (const float*)d_in[11];
    const float* l2w  = (const float*)d_in[12];
    const float* l2b  = (const float*)d_in[13];
    float* out = (float*)d_out;

    const int N = in_sizes[0] / 128;
    const int E = in_sizes[1] / 2;
    const int G = out_size / 2;
    const int* src = ei;
    const int* dst = ei + E;

    const int NP = (N + SB - 1) / SB;     // fine-bin count (=200 for N=100000)

    char* w = (char*)d_ws;
    auto alloc = [&](size_t bytes) {
        char* p = w;
        w += (bytes + 255) & ~(size_t)255;
        return p;
    };
    float* dis      = (float*)alloc((size_t)N * 4);
    int*   rowptr   = (int*)  alloc((size_t)(N + 1) * 4);
    int*   csr_src  = (int*)  alloc((size_t)E * 4);
    int*   blk_hist = (int*)  alloc((size_t)NBLK * NP * 4);
    int*   total    = (int*)  alloc((size_t)NP * 4);
    int*   sbase    = (int*)  alloc((size_t)(NP + 1) * 4);
    int*   blk_off  = (int*)  alloc((size_t)NBLK * NP * 4);
    uint2* pairs    = (uint2*)alloc((size_t)E * 8);
    float* hpsA     = (float*)alloc((size_t)N * 32 * 4);
    float* hpsB     = (float*)alloc((size_t)N * 32 * 4);
    float* catb     = (float*)alloc((size_t)N * 96 * 4);
    int*   idx      = (int*)  alloc((size_t)G * 4);

    const int nodes_bl = (N * 32 + 255) / 256;   // 8 nodes per 256-thr block
    const int gemm_bl  = (N + 63) / 64;

    k_hist  <<<NBLK, 256, 0, stream>>>(dst, blk_hist, E, NP);
    k_total <<<NP,   256, 0, stream>>>(blk_hist, total, NP);
    k_sbase <<<1,    256, 0, stream>>>(total, sbase, NP);
    k_binoff<<<NP,  NBLK, 0, stream>>>(blk_hist, sbase, blk_off, NP);
    k_split <<<NBLK, 256, 0, stream>>>(src, dst, blk_off, pairs, E, NP);
    k_place <<<NP,   512, 0, stream>>>(pairs, sbase, rowptr, dis, csr_src, N, NP);

    // layer 1 GEMM, then agg layers (2/3 GEMMs fused into agg epilogues)
    k_gemm1<<<gemm_bl, 128, 0, stream>>>(x, W1, dis, hpsA, N);
    k_agg<true ><<<nodes_bl, 256, 0, stream>>>(hpsA, rowptr, csr_src, dis, b1, catb + 0,  N, W2, hpsB);
    k_agg<true ><<<nodes_bl, 256, 0, stream>>>(hpsB, rowptr, csr_src, dis, b2, catb + 32, N, W3, hpsA);
    k_agg<false><<<nodes_bl, 256, 0, stream>>>(hpsA, rowptr, csr_src, dis, b3, catb + 64, N, nullptr, nullptr);

    k_idx<<<(G + 255) / 256, 256, 0, stream>>>(batch, idx, N, G);
    k_head<<<G, 128, 0, stream>>>(catb, idx, l1w, l1b, l2w, l2b, out);
}

// Round 10
// 228.404 us; speedup vs baseline: 1.5836x; 1.0280x over previous
//
#include <hip/hip_runtime.h>
#include <math.h>

// ---------------------------------------------------------------------------
// GCN: 3 layers (128->32->32->32). CSR build with NO scattered global stores
// and NO redundant re-reads (hist/total/sbase/binoff/split/place pipeline).
// Aggregation gathers fp16 hps rows (64B = 1 L2 sector per edge, f32 accum).
// Algebra: agg[g] = tanh( dis[g]*(sum_{e:dst=g} hps[src_e] + hps[g]) + b ),
//          hps = dis ⊙ (h @ W); layer-2/3 GEMMs fused into agg epilogue.
// Assumes N <= 128000 (fine-bin count <= 256); harness uses N=100000.
// ---------------------------------------------------------------------------

typedef int      int4v   __attribute__((ext_vector_type(4)));
typedef float    float4v __attribute__((ext_vector_type(4)));
typedef _Float16 half4v  __attribute__((ext_vector_type(4)));

#define NBLK 256            // blocks in hist/split (hist partition == split partition)
#define SB   500            // nodes per fine bin
#define CAPE 10240          // LDS stage capacity (bin mean 8000, std ~90)

// ---- per-block fine histogram: blk_hist[b*NP + f] ----
__global__ void k_hist(const int* __restrict__ dst, int* __restrict__ blk_hist,
                       int E, int NP) {
    __shared__ int h[256];
    for (int i = threadIdx.x; i < NP; i += 256) h[i] = 0;
    __syncthreads();
    const int4v* d4 = (const int4v*)dst;
    int nv = E >> 2;
    int stride = gridDim.x * blockDim.x;
    for (int i = blockIdx.x * blockDim.x + threadIdx.x; i < nv; i += stride) {
        int4v d = __builtin_nontemporal_load(&d4[i]);
#pragma unroll
        for (int j = 0; j < 4; ++j) atomicAdd(&h[d[j] / SB], 1);
    }
    if (blockIdx.x == 0) {
        for (int e = (nv << 2) + threadIdx.x; e < E; e += blockDim.x)
            atomicAdd(&h[dst[e] / SB], 1);
    }
    __syncthreads();
    for (int i = threadIdx.x; i < NP; i += 256)
        blk_hist[blockIdx.x * NP + i] = h[i];
}

// ---- per-bin totals (block f reduces column f over NBLK blocks) ----
__global__ void k_total(const int* __restrict__ blk_hist, int* __restrict__ total, int NP) {
    __shared__ int s[256];
    int f = blockIdx.x;
    int acc = 0;
    for (int b = threadIdx.x; b < NBLK; b += 256) acc += blk_hist[b * NP + f];
    s[threadIdx.x] = acc;
    __syncthreads();
    for (int off = 128; off > 0; off >>= 1) {
        if (threadIdx.x < off) s[threadIdx.x] += s[threadIdx.x + off];
        __syncthreads();
    }
    if (threadIdx.x == 0) total[f] = s[0];
}

// ---- exclusive scan of totals -> sbase[0..NP], sbase[NP]=E ----
__global__ void k_sbase(const int* __restrict__ total, int* __restrict__ sbase, int NP) {
    __shared__ int s[256];
    int t = threadIdx.x;
    int v = (t < NP) ? total[t] : 0;
    s[t] = v;
    __syncthreads();
    for (int off = 1; off < 256; off <<= 1) {
        int u = (t >= off) ? s[t - off] : 0;
        __syncthreads();
        s[t] += u;
        __syncthreads();
    }
    if (t < NP) sbase[t] = s[t] - v;
    if (t == NP - 1) sbase[NP] = s[t];
}

// ---- per-(block,bin) window offsets: blk_off[b*NP+f] (block f scans bin f) ----
__global__ void k_binoff(const int* __restrict__ blk_hist, const int* __restrict__ sbase,
                         int* __restrict__ blk_off, int NP) {
    __shared__ int s[NBLK];
    int f = blockIdx.x;
    int b = threadIdx.x;      // NBLK threads
    int v = blk_hist[b * NP + f];
    s[b] = v;
    __syncthreads();
    for (int off = 1; off < NBLK; off <<= 1) {
        int u = (b >= off) ? s[b - off] : 0;
        __syncthreads();
        s[b] += u;
        __syncthreads();
    }
    blk_off[b * NP + f] = sbase[f] + s[b] - v;
}

// ---- scatter edges directly into fine-bin regions ----
__global__ void k_split(const int* __restrict__ src, const int* __restrict__ dst,
                        const int* __restrict__ blk_off, uint2* __restrict__ pairs,
                        int E, int NP) {
    __shared__ int goff[256];
    for (int f = threadIdx.x; f < NP; f += 256)
        goff[f] = blk_off[blockIdx.x * NP + f];
    __syncthreads();
    const int4v* d4 = (const int4v*)dst;
    const int4v* s4 = (const int4v*)src;
    int nv = E >> 2;
    int stride = gridDim.x * blockDim.x;
    for (int i = blockIdx.x * blockDim.x + threadIdx.x; i < nv; i += stride) {
        int4v d = __builtin_nontemporal_load(&d4[i]);
        int4v s = __builtin_nontemporal_load(&s4[i]);
#pragma unroll
        for (int j = 0; j < 4; ++j) {
            int f = d[j] / SB;
            int pos = atomicAdd(&goff[f], 1);
            pairs[pos] = make_uint2((unsigned)s[j], (unsigned)d[j]);
        }
    }
    if (blockIdx.x == 0) {
        for (int e = (nv << 2) + threadIdx.x; e < E; e += blockDim.x) {
            int f = dst[e] / SB;
            int pos = atomicAdd(&goff[f], 1);
            pairs[pos] = make_uint2((unsigned)src[e], (unsigned)dst[e]);
        }
    }
}

// ---- place: per fine bin, LDS count/scan/scatter, coalesced global writes ----
__global__ void __launch_bounds__(512)
k_place(const uint2* __restrict__ pairs, const int* __restrict__ sbase,
        int* __restrict__ rowptr, float* __restrict__ dis,
        int* __restrict__ csr_src, int N, int NP) {
    __shared__ int lcnt[SB];
    __shared__ int lrp[SB + 1];
    __shared__ int sc[512];
    __shared__ int stage[CAPE];
    int f = blockIdx.x;
    int lo = f * SB;
    if (lo >= N) return;
    int hi = lo + SB; if (hi > N) hi = N;
    int sbc = hi - lo;
    int p0 = sbase[f], p1 = sbase[f + 1];
    int base = p0;
    int tid = threadIdx.x;
    for (int i = tid; i < sbc; i += 512) lcnt[i] = 0;
    __syncthreads();
    // pass A: count (4-way unrolled for MLP)
    {
        int i = p0 + tid;
        for (; i + 3 * 512 < p1; i += 4 * 512) {
            uint2 a = pairs[i], c = pairs[i + 512], d = pairs[i + 1024], e = pairs[i + 1536];
            unsigned la = a.y - lo, lc = c.y - lo, ld = d.y - lo, le = e.y - lo;
            if (la < (unsigned)sbc) atomicAdd(&lcnt[la], 1);
            if (lc < (unsigned)sbc) atomicAdd(&lcnt[lc], 1);
            if (ld < (unsigned)sbc) atomicAdd(&lcnt[ld], 1);
            if (le < (unsigned)sbc) atomicAdd(&lcnt[le], 1);
        }
        for (; i < p1; i += 512) {
            unsigned ly = pairs[i].y - lo;
            if (ly < (unsigned)sbc) atomicAdd(&lcnt[ly], 1);
        }
    }
    __syncthreads();
    // dis (coalesced)
    for (int i = tid; i < sbc; i += 512) dis[lo + i] = rsqrtf(1.0f + (float)lcnt[i]);
    // exclusive scan lcnt -> lrp
    int v = (tid < sbc) ? lcnt[tid] : 0;
    sc[tid] = v;
    __syncthreads();
    for (int off = 1; off < 512; off <<= 1) {
        int u = (tid >= off) ? sc[tid - off] : 0;
        __syncthreads();
        sc[tid] += u;
        __syncthreads();
    }
    if (tid < sbc) lrp[tid] = sc[tid] - v;
    if (tid == 511) lrp[sbc] = sc[511];
    __syncthreads();
    int T = lrp[sbc];
    // rowptr (coalesced)
    for (int i = tid; i < sbc; i += 512) rowptr[lo + i] = base + lrp[i];
    if (hi == N && tid == 0) rowptr[N] = base + T;
    // pass B: scatter into LDS stage (or global fallback if T > CAPE)
    for (int i = tid; i < sbc; i += 512) lcnt[i] = 0;
    __syncthreads();
    {
        int i = p0 + tid;
        for (; i + 3 * 512 < p1; i += 4 * 512) {
            uint2 a = pairs[i], c = pairs[i + 512], d = pairs[i + 1024], e = pairs[i + 1536];
#pragma unroll
            for (int j = 0; j < 4; ++j) {
                uint2 p = (j == 0) ? a : (j == 1) ? c : (j == 2) ? d : e;
                unsigned ly = p.y - lo;
                if (ly < (unsigned)sbc) {
                    int slot = lrp[ly] + atomicAdd(&lcnt[ly], 1);
                    if (T <= CAPE) stage[slot] = (int)p.x;
                    else           csr_src[base + slot] = (int)p.x;
                }
            }
        }
        for (; i < p1; i += 512) {
            uint2 p = pairs[i];
            unsigned ly = p.y - lo;
            if (ly < (unsigned)sbc) {
                int slot = lrp[ly] + atomicAdd(&lcnt[ly], 1);
                if (T <= CAPE) stage[slot] = (int)p.x;
                else           csr_src[base + slot] = (int)p.x;
            }
        }
    }
    __syncthreads();
    if (T <= CAPE)
        for (int j = tid; j < T; j += 512) csr_src[base + j] = stage[j];
}

// ---- layer-1 GEMM: hps[n,32] = fp16( dis ⊙ (x[n,128] @ W[128,32]) ) ----
__global__ void k_gemm1(const float* __restrict__ h, const float* __restrict__ W,
                        const float* __restrict__ dis, _Float16* __restrict__ hps, int n) {
    __shared__ float sW[128 * 32];          // [k][col]
    __shared__ float sh[64 * 132];          // [row][k], pad 132
    int tid = threadIdx.x;
    int row0 = blockIdx.x * 64;
    for (int j = tid; j < 1024; j += 128)
        *(float4*)&sW[j * 4] = *(const float4*)&W[j * 4];
    for (int j = tid; j < 2048; j += 128) {
        int r = j >> 5, c4 = j & 31;
        float4v v = {0.f, 0.f, 0.f, 0.f};
        if (row0 + r < n)
            v = __builtin_nontemporal_load((const float4v*)&h[(size_t)(row0 + r) * 128 + c4 * 4]);
        *(float4v*)&sh[r * 132 + c4 * 4] = v;
    }
    __syncthreads();
    int rg = tid >> 3;      // 0..15 -> 4 rows each
    int cg = tid & 7;       // 0..7  -> 4 cols each
    float acc[4][4] = {};
    const float* shp = &sh[(rg * 4) * 132];
    const float* swp = &sW[cg * 4];
#pragma unroll 8
    for (int k4 = 0; k4 < 32; ++k4) {
        float4 hv[4], wv[4];
#pragma unroll
        for (int r = 0; r < 4; ++r) hv[r] = *(const float4*)&shp[r * 132 + k4 * 4];
#pragma unroll
        for (int t = 0; t < 4; ++t) wv[t] = *(const float4*)&swp[(k4 * 4 + t) * 32];
#pragma unroll
        for (int r = 0; r < 4; ++r) {
            const float hr[4] = {hv[r].x, hv[r].y, hv[r].z, hv[r].w};
#pragma unroll
            for (int t = 0; t < 4; ++t) {
                acc[r][0] += hr[t] * wv[t].x;
                acc[r][1] += hr[t] * wv[t].y;
                acc[r][2] += hr[t] * wv[t].z;
                acc[r][3] += hr[t] * wv[t].w;
            }
        }
    }
#pragma unroll
    for (int r = 0; r < 4; ++r) {
        int row = row0 + rg * 4 + r;
        if (row < n) {
            float dv = dis[row];
            half4v o = { (_Float16)(acc[r][0] * dv), (_Float16)(acc[r][1] * dv),
                         (_Float16)(acc[r][2] * dv), (_Float16)(acc[r][3] * dv) };
            *(half4v*)&hps[(size_t)row * 32 + cg * 4] = o;
        }
    }
}

// ---- aggregation (+ optional fused next-layer GEMM epilogue) ----
// 32-lane group per node; 8-way batched fp16 row gathers (64B/edge), f32 accum.
template <bool FUSE>
__global__ void k_agg(const _Float16* __restrict__ hps, const int* __restrict__ rowptr,
                      const int* __restrict__ csr_src, const float* __restrict__ dis,
                      const float* __restrict__ bias, float* __restrict__ outc,
                      int n, const float* __restrict__ Wn, _Float16* __restrict__ hpsn) {
    __shared__ float sW[32 * 32];
    if (FUSE) {
        for (int i = threadIdx.x; i < 1024; i += 256) sW[i] = Wn[i];
        __syncthreads();
    }
    int g    = (blockIdx.x * blockDim.x + threadIdx.x) >> 5;
    int lane = threadIdx.x & 31;
    if (g >= n) return;
    float acc = (float)hps[(size_t)g * 32 + lane];   // self term
    int e0 = rowptr[g], e1 = rowptr[g + 1];
    int e = e0;
    while (e < e1) {
        int m = e1 - e; if (m > 32) m = 32;
        int sv = (e + lane < e1) ? __builtin_nontemporal_load(&csr_src[e + lane]) : 0;
        int k = 0;
        for (; k + 8 <= m; k += 8) {
            float v[8];
#pragma unroll
            for (int j = 0; j < 8; ++j) {
                int s = __shfl(sv, k + j, 32);
                v[j] = (float)hps[(size_t)s * 32 + lane];
            }
            acc += ((v[0] + v[1]) + (v[2] + v[3])) + ((v[4] + v[5]) + (v[6] + v[7]));
        }
        if (k + 4 <= m) {
            float v[4];
#pragma unroll
            for (int j = 0; j < 4; ++j) {
                int s = __shfl(sv, k + j, 32);
                v[j] = (float)hps[(size_t)s * 32 + lane];
            }
            acc += (v[0] + v[1]) + (v[2] + v[3]);
            k += 4;
        }
        for (; k < m; ++k) {
            int s = __shfl(sv, k, 32);
            acc += (float)hps[(size_t)s * 32 + lane];
        }
        e += m;
    }
    float dg = dis[g];
    float v = tanhf(dg * acc + bias[lane]);
    __builtin_nontemporal_store(v, &outc[(size_t)g * 96 + lane]);
    if (FUSE) {
        float a2 = 0.0f;
#pragma unroll
        for (int k = 0; k < 32; ++k)
            a2 += __shfl(v, k, 32) * sW[k * 32 + lane];
        hpsn[(size_t)g * 32 + lane] = (_Float16)(dg * a2);
    }
}

__global__ void k_idx(const int* __restrict__ batch, int* __restrict__ idx, int n, int g) {
    int i = blockIdx.x * blockDim.x + threadIdx.x;
    if (i >= g) return;
    int lo = 0, hi = n;
    while (lo < hi) {
        int mid = (lo + hi) >> 1;
        if (batch[mid] < i) lo = mid + 1; else hi = mid;
    }
    idx[i] = lo;
}

__global__ void k_head(const float* __restrict__ cat, const int* __restrict__ idx,
                       const float* __restrict__ w1, const float* __restrict__ b1,
                       const float* __restrict__ w2, const float* __restrict__ b2,
                       float* __restrict__ out) {
    __shared__ float gv[96];
    __shared__ float s0[128];
    __shared__ float s1[128];
    int g = blockIdx.x, t = threadIdx.x;
    int node = idx[g];
    if (t < 96) gv[t] = cat[(size_t)node * 96 + t];
    __syncthreads();
    float acc = b1[t];
#pragma unroll 8
    for (int i = 0; i < 96; ++i) acc += gv[i] * w1[i * 128 + t];
    float h = fmaxf(acc, 0.0f);
    s0[t] = h * w2[t * 2 + 0];
    s1[t] = h * w2[t * 2 + 1];
    __syncthreads();
    for (int off = 64; off > 0; off >>= 1) {
        if (t < off) { s0[t] += s0[t + off]; s1[t] += s1[t + off]; }
        __syncthreads();
    }
    if (t == 0) {
        float l0 = s0[0] + b2[0];
        float l1 = s1[0] + b2[1];
        float m  = fmaxf(l0, l1);
        float lse = m + logf(expf(l0 - m) + expf(l1 - m));
        out[(size_t)g * 2 + 0] = l0 - lse;
        out[(size_t)g * 2 + 1] = l1 - lse;
    }
}

extern "C" void kernel_launch(void* const* d_in, const int* in_sizes, int n_in,
                              void* d_out, int out_size, void* d_ws, size_t ws_size,
                              hipStream_t stream) {
    const float* x    = (const float*)d_in[0];
    const int*   ei   = (const int*)d_in[1];
    const int*   batch= (const int*)d_in[2];
    const float* W1   = (const float*)d_in[4];
    const float* b1   = (const float*)d_in[5];
    const float* W2   = (const float*)d_in[6];
    const float* b2   = (const float*)d_in[7];
    const float* W3   = (const float*)d_in[8];
    const float* b3   = (const float*)d_in[9];
    const float* l1w  = (const float*)d_in[10];
    const float* l1b  = (const float*)d_in[11];
    const float* l2w  = (const float*)d_in[12];
    const float* l2b  = (const float*)d_in[13];
    float* out = (float*)d_out;

    const int N = in_sizes[0] / 128;
    const int E = in_sizes[1] / 2;
    const int G = out_size / 2;
    const int* src = ei;
    const int* dst = ei + E;

    const int NP = (N + SB - 1) / SB;     // fine-bin count (=200 for N=100000)

    char* w = (char*)d_ws;
    auto alloc = [&](size_t bytes) {
        char* p = w;
        w += (bytes + 255) & ~(size_t)255;
        return p;
    };
    float*    dis      = (float*)   alloc((size_t)N * 4);
    int*      rowptr   = (int*)     alloc((size_t)(N + 1) * 4);
    int*      csr_src  = (int*)     alloc((size_t)E * 4);
    int*      blk_hist = (int*)     alloc((size_t)NBLK * NP * 4);
    int*      total    = (int*)     alloc((size_t)NP * 4);
    int*      sbase    = (int*)     alloc((size_t)(NP + 1) * 4);
    int*      blk_off  = (int*)     alloc((size_t)NBLK * NP * 4);
    uint2*    pairs    = (uint2*)   alloc((size_t)E * 8);
    _Float16* hpsA     = (_Float16*)alloc((size_t)N * 32 * 2);
    _Float16* hpsB     = (_Float16*)alloc((size_t)N * 32 * 2);
    float*    catb     = (float*)   alloc((size_t)N * 96 * 4);
    int*      idx      = (int*)     alloc((size_t)G * 4);

    const int nodes_bl = (N * 32 + 255) / 256;   // 8 nodes per 256-thr block
    const int gemm_bl  = (N + 63) / 64;

    k_hist  <<<NBLK, 256, 0, stream>>>(dst, blk_hist, E, NP);
    k_total <<<NP,   256, 0, stream>>>(blk_hist, total, NP);
    k_sbase <<<1,    256, 0, stream>>>(total, sbase, NP);
    k_binoff<<<NP,  NBLK, 0, stream>>>(blk_hist, sbase, blk_off, NP);
    k_split <<<NBLK, 256, 0, stream>>>(src, dst, blk_off, pairs, E, NP);
    k_place <<<NP,   512, 0, stream>>>(pairs, sbase, rowptr, dis, csr_src, N, NP);

    // layer 1 GEMM, then agg layers (2/3 GEMMs fused into agg epilogues)
    k_gemm1<<<gemm_bl, 128, 0, stream>>>(x, W1, dis, hpsA, N);
    k_agg<true ><<<nodes_bl, 256, 0, stream>>>(hpsA, rowptr, csr_src, dis, b1, catb + 0,  N, W2, hpsB);
    k_agg<true ><<<nodes_bl, 256, 0, stream>>>(hpsB, rowptr, csr_src, dis, b2, catb + 32, N, W3, hpsA);
    k_agg<false><<<nodes_bl, 256, 0, stream>>>(hpsA, rowptr, csr_src, dis, b3, catb + 64, N, nullptr, nullptr);

    k_idx<<<(G + 255) / 256, 256, 0, stream>>>(batch, idx, N, G);
    k_head<<<G, 128, 0, stream>>>(catb, idx, l1w, l1b, l2w, l2b, out);
}